// Round 12
// baseline (451.679 us; speedup 1.0000x reference)
//
#include <hip/hip_runtime.h>

#define NB 8
#define NC 128
#define NN 256
#define NK 96
#define NA 512
#define NM 768   // NN + NA
#define NBLK 256 // grid size: <= CU count x 2 via launch_bounds -> all co-resident

typedef __attribute__((ext_vector_type(8))) short bf16x8;
typedef __attribute__((ext_vector_type(4))) float f32x4;
typedef __attribute__((ext_vector_type(4))) unsigned short u16x4;

__device__ __forceinline__ float wave_allreduce_add(float s) {
    for (int o = 1; o < 64; o <<= 1) s += __shfl_xor(s, o, 64);
    return s;
}

__device__ __forceinline__ unsigned short f2bf(float x) {
    unsigned u = __float_as_uint(x);
    unsigned r = (u + 0x7FFFu + ((u >> 16) & 1u)) >> 16;
    return (unsigned short)r;
}
__device__ __forceinline__ float bf2f(unsigned short h) {
    return __uint_as_float((unsigned)h << 16);
}

__device__ __forceinline__ unsigned long long pack_key(float v, unsigned idx) {
    unsigned u = __float_as_uint(v);
    u = (u & 0x80000000u) ? ~u : (u | 0x80000000u);
    return ((unsigned long long)u << 32) | (unsigned long long)(0xFFFFFFFFu - idx);
}

__device__ __forceinline__ void ins4(unsigned long long v, unsigned long long* k) {
    if (v > k[3]) {
        if (v > k[1]) {
            if (v > k[0]) { k[3] = k[2]; k[2] = k[1]; k[1] = k[0]; k[0] = v; }
            else         { k[3] = k[2]; k[2] = k[1]; k[1] = v; }
        } else {
            if (v > k[2]) { k[3] = k[2]; k[2] = v; }
            else          { k[3] = v; }
        }
    }
}

__device__ __forceinline__ void merge_top4(unsigned long long* k) {
#pragma unroll
    for (int d = 1; d < 64; d <<= 1) {
        unsigned long long p0 = __shfl_xor(k[0], d, 64);
        unsigned long long p1 = __shfl_xor(k[1], d, 64);
        unsigned long long p2 = __shfl_xor(k[2], d, 64);
        unsigned long long p3 = __shfl_xor(k[3], d, 64);
        unsigned long long c0 = k[0] > p3 ? k[0] : p3;
        unsigned long long c1 = k[1] > p2 ? k[1] : p2;
        unsigned long long c2 = k[2] > p1 ? k[2] : p1;
        unsigned long long c3 = k[3] > p0 ? k[3] : p0;
        unsigned long long d0 = c0 > c2 ? c0 : c2, d2 = c0 > c2 ? c2 : c0;
        unsigned long long d1 = c1 > c3 ? c1 : c3, d3 = c1 > c3 ? c3 : c1;
        k[0] = d0 > d1 ? d0 : d1; k[1] = d0 > d1 ? d1 : d0;
        k[2] = d2 > d3 ? d2 : d3; k[3] = d2 > d3 ? d3 : d2;
    }
}

// ---- two-level software grid barrier (device-scope atomics; bar zeroed per launch) ----
// layout (ints): cnt[g]=bar[g*32] g<8 ; root=bar[320] ; gen=bar[384]
__device__ __forceinline__ void grid_barrier(int* bar) {
    __syncthreads();
    if (threadIdx.x == 0) {
        int* cnt  = bar + (blockIdx.x & 7) * 32;
        int* root = bar + 320;
        int* gen  = bar + 384;
        int mygen = __hip_atomic_load(gen, __ATOMIC_ACQUIRE, __HIP_MEMORY_SCOPE_AGENT);
        __threadfence();   // release: flush this block's prior writes to coherence point
        int old = __hip_atomic_fetch_add(cnt, 1, __ATOMIC_ACQ_REL, __HIP_MEMORY_SCOPE_AGENT);
        if (old == 31) {
            __hip_atomic_store(cnt, 0, __ATOMIC_RELAXED, __HIP_MEMORY_SCOPE_AGENT);
            int ro = __hip_atomic_fetch_add(root, 1, __ATOMIC_ACQ_REL, __HIP_MEMORY_SCOPE_AGENT);
            if (ro == 7) {
                __hip_atomic_store(root, 0, __ATOMIC_RELAXED, __HIP_MEMORY_SCOPE_AGENT);
                __threadfence();
                __hip_atomic_fetch_add(gen, 1, __ATOMIC_RELEASE, __HIP_MEMORY_SCOPE_AGENT);
            } else {
                long sp = 0;
                while (__hip_atomic_load(gen, __ATOMIC_ACQUIRE, __HIP_MEMORY_SCOPE_AGENT) == mygen) {
                    __builtin_amdgcn_s_sleep(2);
                    if (++sp > (1L << 24)) break;   // bailout: fail loud, never hang
                }
            }
        } else {
            long sp = 0;
            while (__hip_atomic_load(gen, __ATOMIC_ACQUIRE, __HIP_MEMORY_SCOPE_AGENT) == mygen) {
                __builtin_amdgcn_s_sleep(2);
                if (++sp > (1L << 24)) break;
            }
        }
        __threadfence();   // acquire: invalidate stale cache before consuming others' data
    }
    __syncthreads();
}

// ---- one MFMA propagation tile (round-11 validated body) ----
__device__ __forceinline__ void prop_tile(const unsigned short* __restrict__ W16,
                                          const float* __restrict__ dis,
                                          const unsigned short* __restrict__ Zin,
                                          unsigned short* __restrict__ Zout,
                                          float* __restrict__ Xh, float coef,
                                          int b, int m0, int c0, int tid) {
    int w = tid >> 6, l = tid & 63;
    int wm = w >> 1, wc = w & 1;
    int lr = l & 15, lg = l >> 4;
    const unsigned short* Ap = W16 + ((size_t)b * NM + m0 + wm * 16 + lr) * NM + lg * 8;
    const unsigned short* Bp = Zin + ((size_t)b * NC + c0 + wc * 32 + lr) * NM + lg * 8;
    f32x4 acc[2];
#pragma unroll
    for (int f = 0; f < 2; f++) { acc[f][0] = 0.f; acc[f][1] = 0.f; acc[f][2] = 0.f; acc[f][3] = 0.f; }
    bf16x8 a0 = *(const bf16x8*)(Ap);
    bf16x8 b0[2];
#pragma unroll
    for (int f = 0; f < 2; f++) b0[f] = *(const bf16x8*)(Bp + (size_t)(f * 16) * NM);
    for (int k0 = 0; k0 < NM - 32; k0 += 32) {
        bf16x8 a1 = *(const bf16x8*)(Ap + k0 + 32);
        bf16x8 b1[2];
#pragma unroll
        for (int f = 0; f < 2; f++) b1[f] = *(const bf16x8*)(Bp + (size_t)(f * 16) * NM + k0 + 32);
#pragma unroll
        for (int f = 0; f < 2; f++)
            acc[f] = __builtin_amdgcn_mfma_f32_16x16x32_bf16(a0, b0[f], acc[f], 0, 0, 0);
        a0 = a1;
#pragma unroll
        for (int f = 0; f < 2; f++) b0[f] = b1[f];
    }
#pragma unroll
    for (int f = 0; f < 2; f++)
        acc[f] = __builtin_amdgcn_mfma_f32_16x16x32_bf16(a0, b0[f], acc[f], 0, 0, 0);
    int mb = m0 + wm * 16 + lg * 4;
    f32x4 dv = *(const f32x4*)(dis + b * NM + mb);
    bool doXh = (m0 < NN);
#pragma unroll
    for (int f = 0; f < 2; f++) {
        int c = c0 + wc * 32 + f * 16 + lr;
        size_t off = ((size_t)b * NC + c) * NM + mb;
        u16x4 zi = *(const u16x4*)(Zin + off);
        u16x4 zo;
        f32x4 xh;
        size_t offh = ((size_t)b * NC + c) * NN + mb;
        if (doXh) xh = *(const f32x4*)(Xh + offh);
#pragma unroll
        for (int r = 0; r < 4; r++) {
            float o = dv[r] * (acc[f][r] + bf2f(zi[r]));
            if (doXh) xh[r] += coef * o;
            zo[r] = f2bf(dv[r] * o);
        }
        if (doXh) *(f32x4*)(Xh + offh) = xh;
        *(u16x4*)(Zout + off) = zo;
    }
}

// ---- last propagation tile (m<256): writes X_hat directly (round-11 validated) ----
__device__ __forceinline__ void prop_last_tile(const unsigned short* __restrict__ W16,
                                               const float* __restrict__ dis,
                                               const unsigned short* __restrict__ Zin,
                                               const float* __restrict__ Xh,
                                               float* __restrict__ out_xhat, float coef,
                                               int b, int m0, int c0, int tid) {
    int w = tid >> 6, l = tid & 63;
    int wm = w >> 1, wc = w & 1;
    int lr = l & 15, lg = l >> 4;
    const unsigned short* Ap = W16 + ((size_t)b * NM + m0 + wm * 16 + lr) * NM + lg * 8;
    const unsigned short* Bp = Zin + ((size_t)b * NC + c0 + wc * 32 + lr) * NM + lg * 8;
    f32x4 acc[2];
#pragma unroll
    for (int f = 0; f < 2; f++) { acc[f][0] = 0.f; acc[f][1] = 0.f; acc[f][2] = 0.f; acc[f][3] = 0.f; }
    bf16x8 a0 = *(const bf16x8*)(Ap);
    bf16x8 b0[2];
#pragma unroll
    for (int f = 0; f < 2; f++) b0[f] = *(const bf16x8*)(Bp + (size_t)(f * 16) * NM);
    for (int k0 = 0; k0 < NM - 32; k0 += 32) {
        bf16x8 a1 = *(const bf16x8*)(Ap + k0 + 32);
        bf16x8 b1[2];
#pragma unroll
        for (int f = 0; f < 2; f++) b1[f] = *(const bf16x8*)(Bp + (size_t)(f * 16) * NM + k0 + 32);
#pragma unroll
        for (int f = 0; f < 2; f++)
            acc[f] = __builtin_amdgcn_mfma_f32_16x16x32_bf16(a0, b0[f], acc[f], 0, 0, 0);
        a0 = a1;
#pragma unroll
        for (int f = 0; f < 2; f++) b0[f] = b1[f];
    }
#pragma unroll
    for (int f = 0; f < 2; f++)
        acc[f] = __builtin_amdgcn_mfma_f32_16x16x32_bf16(a0, b0[f], acc[f], 0, 0, 0);
    int mb = m0 + wm * 16 + lg * 4;   // < 256
    f32x4 dv = *(const f32x4*)(dis + b * NM + mb);
#pragma unroll
    for (int f = 0; f < 2; f++) {
        int c = c0 + wc * 32 + f * 16 + lr;
        size_t offM = ((size_t)b * NC + c) * NM + mb;
        u16x4 zi = *(const u16x4*)(Zin + offM);
        f32x4 xh = *(const f32x4*)(Xh + ((size_t)b * NC + c) * NN + mb);
        f32x4 ov;
#pragma unroll
        for (int r = 0; r < 4; r++) {
            float o = dv[r] * (acc[f][r] + bf2f(zi[r]));
            ov[r] = xh[r] + coef * o;
        }
        *(f32x4*)(out_xhat + ((size_t)b * NC + c) * NN + mb) = ov;
    }
}

// ================= whole pipeline: ONE normal kernel + software barriers =================
__global__ __launch_bounds__(256, 2) void k_mega(
    const float* __restrict__ feat, const float* __restrict__ adj,
    const float* __restrict__ tf, const float* __restrict__ mem_adj,
    float* __restrict__ memN_T, float* __restrict__ tfT, float* __restrict__ Xn,
    float* __restrict__ sim, float* __restrict__ simT,
    float* __restrict__ sc_adj, float* __restrict__ inv_edge,
    float* __restrict__ dmem_inv, float* __restrict__ isn,
    float* __restrict__ dis, float* __restrict__ W, float* __restrict__ Xh,
    unsigned short* __restrict__ W16, unsigned short* __restrict__ Z0,
    unsigned short* __restrict__ Z1,
    float* __restrict__ out_xhat, float* __restrict__ out_xe, int* bar)
{
    __shared__ float smem[2 * 16 * (NK + 1)];   // 12.4 KB
    int tid = threadIdx.x;
    int lane = tid & 63;
    int gwave = blockIdx.x * 4 + (tid >> 6);    // 0..1023
    const int GW = NBLK * 4;

    // ---- P1: normalize (1 wave/row, 2 elems/lane) + degrees ----
    {
        const int ROWS = NA + NB * NN;                         // 2560
        const int T1 = ROWS + NK + NB * NK + NB * NN;          // 5472
        for (int t = gwave; t < T1; t += GW) {
            if (t < NA) {
                int a = t;
                float v0 = tf[a * NC + lane], v1 = tf[a * NC + lane + 64];
                float s = wave_allreduce_add(v0 * v0 + v1 * v1);
                float inv = 1.0f / fmaxf(sqrtf(s), 1e-12f);
                memN_T[lane * NA + a] = v0 * inv;
                memN_T[(lane + 64) * NA + a] = v1 * inv;
                tfT[lane * NA + a] = v0;
                tfT[(lane + 64) * NA + a] = v1;
            } else if (t < ROWS) {
                int g = t - NA;                                // b*NN + n
                int b = g >> 8, n = g & 255;
                float v0 = feat[((size_t)b * NC + lane) * NN + n];
                float v1 = feat[((size_t)b * NC + lane + 64) * NN + n];
                float s = wave_allreduce_add(v0 * v0 + v1 * v1);
                float inv = 1.0f / fmaxf(sqrtf(s), 1e-12f);
                Xn[(size_t)g * NC + lane] = v0 * inv;
                Xn[(size_t)g * NC + lane + 64] = v1 * inv;
            } else {
                int wid = t - ROWS;
                if (wid < NK) {
                    float s = 0.f;
                    for (int a = lane; a < NA; a += 64) s += mem_adj[(size_t)a * NK + wid];
                    s = wave_allreduce_add(s);
                    if (lane == 0) dmem_inv[wid] = 1.0f / (s + 1e-8f);
                } else if (wid < NK + NB * NK) {
                    int w2 = wid - NK;
                    int b = w2 / NK, k = w2 % NK;
                    float s = 0.f;
                    for (int n = lane; n < NN; n += 64) s += adj[(size_t)(b * NN + n) * NK + k];
                    s = wave_allreduce_add(s);
                    if (lane == 0) {
                        sc_adj[w2] = 1.0f / (s + 1e-8f);
                        inv_edge[w2] = 1.0f / fmaxf(s, 1e-8f);
                    }
                } else {
                    int w3 = wid - NK - NB * NK;               // b*NN + n
                    const float* row = adj + (size_t)w3 * NK;
                    float s = (lane < NK) ? row[lane] : 0.f;
                    if (lane + 64 < NK) s += row[lane + 64];   // NK=96
                    s = wave_allreduce_add(s);
                    if (lane == 0) isn[w3] = 1.0f / sqrtf(fmaxf(s, 1e-8f));
                }
            }
        }
    }
    grid_barrier(bar);

    // ---- P2: sim (+simT) + W diag blocks + off-diag zero (round-11 k_simwb bodies) ----
    {
        float (*xr)[NC] = (float(*)[NC])smem;
        float (*ta)[NK + 1] = (float(*)[NK + 1])smem;
        float (*tb)[NK + 1] = (float(*)[NK + 1])(smem + 16 * (NK + 1));
        int tx = tid & 15, ty = tid >> 4;
        for (int bt = blockIdx.x; bt < 3840; bt += NBLK) {
            __syncthreads();                                   // smem reuse fence
            if (bt < 256) {
                int g0 = bt * 8;
                int b = g0 >> 8, n0 = g0 & 255;
                for (int i = tid; i < 8 * NC; i += 256) xr[i >> 7][i & 127] = Xn[(size_t)g0 * NC + i];
                __syncthreads();
                float acc0[8] = {0, 0, 0, 0, 0, 0, 0, 0};
                float acc1[8] = {0, 0, 0, 0, 0, 0, 0, 0};
                int a0 = tid, a1 = tid + 256;
                for (int c = 0; c < NC; c++) {
                    float m0 = memN_T[c * NA + a0];
                    float m1 = memN_T[c * NA + a1];
#pragma unroll
                    for (int r = 0; r < 8; r++) { acc0[r] += xr[r][c] * m0; acc1[r] += xr[r][c] * m1; }
                }
#pragma unroll
                for (int r = 0; r < 8; r++) {
                    sim[(size_t)(g0 + r) * NA + a0] = acc0[r];
                    sim[(size_t)(g0 + r) * NA + a1] = acc1[r];
                }
                float* tp0 = simT + ((size_t)(b * NA + a0)) * NN + n0;
                float* tp1 = simT + ((size_t)(b * NA + a1)) * NN + n0;
                f32x4 u, v;
                u[0] = acc0[0]; u[1] = acc0[1]; u[2] = acc0[2]; u[3] = acc0[3];
                v[0] = acc0[4]; v[1] = acc0[5]; v[2] = acc0[6]; v[3] = acc0[7];
                *(f32x4*)tp0 = u; *(f32x4*)(tp0 + 4) = v;
                u[0] = acc1[0]; u[1] = acc1[1]; u[2] = acc1[2]; u[3] = acc1[3];
                v[0] = acc1[4]; v[1] = acc1[5]; v[2] = acc1[6]; v[3] = acc1[7];
                *(f32x4*)tp1 = u; *(f32x4*)(tp1 + 4) = v;
            } else if (bt < 1280) {
                int t = bt - 256;
                int a0 = (t >> 5) * 16, a1 = (t & 31) * 16;
                for (int i = tid; i < 16 * NK; i += 256) {
                    int r = i / NK, j = i % NK;
                    ta[r][j] = mem_adj[(a0 + r) * NK + j] * dmem_inv[j];
                    tb[r][j] = mem_adj[(a1 + r) * NK + j];
                }
                __syncthreads();
                float s = 0.f;
                for (int j = 0; j < NK; j++) s += ta[ty][j] * tb[tx][j];
                int row = NN + a0 + ty, col = NN + a1 + tx;
                for (int b = 0; b < NB; b++) W[(size_t)b * NM * NM + (size_t)row * NM + col] = s;
            } else if (bt < 3328) {
                int t = bt - 1280;
                int n1 = (t & 15) * 16, n0 = ((t >> 4) & 15) * 16, b = t >> 8;
                const float* adjb = adj + (size_t)b * NN * NK;
                const float* scb = sc_adj + b * NK;
                for (int i = tid; i < 16 * NK; i += 256) {
                    int r = i / NK, j = i % NK;
                    ta[r][j] = adjb[(n0 + r) * NK + j] * scb[j];
                    tb[r][j] = adjb[(n1 + r) * NK + j];
                }
                __syncthreads();
                float s = 0.f;
                for (int j = 0; j < NK; j++) s += ta[ty][j] * tb[tx][j];
                W[(size_t)b * NM * NM + (size_t)(n0 + ty) * NM + (n1 + tx)] = s;
            } else {
                int t = bt - 3328;               // [0, 512)
                int b = t >> 6;
                f32x4 z; z[0] = 0.f; z[1] = 0.f; z[2] = 0.f; z[3] = 0.f;
#pragma unroll
                for (int q = 0; q < 4; q++) {
                    int v = (t & 63) * 1024 + q * 256 + tid;   // [0, 65536) f32x4 slots/batch
                    int row, col4;
                    if (v < 32768) { row = v >> 7; col4 = 64 + (v & 127); }
                    else { int v2 = v - 32768; row = 256 + (v2 >> 6); col4 = v2 & 63; }
                    *(f32x4*)(W + (size_t)b * NM * NM + (size_t)row * NM + col4 * 4) = z;
                }
            }
        }
    }
    grid_barrier(bar);

    // ---- P3: top-4 both directions + 25-entry clique scatter into W ----
    {
        const float cval = 1.0f / (5.0f + 1e-8f);
        for (int t = gwave; t < NB * NN + NB * NA; t += GW) {
            unsigned long long k[4] = {0, 0, 0, 0};
            int b, rr[5];
            if (t < NB * NN) {
                b = t >> 8;
                rr[0] = t & 255;
                const float* row = sim + (size_t)t * NA;
#pragma unroll
                for (int q = 0; q < NA / 64; q++) {
                    int a = lane + 64 * q;
                    ins4(pack_key(row[a], (unsigned)a), k);
                }
                merge_top4(k);
#pragma unroll
                for (int q = 0; q < 4; q++) rr[q + 1] = NN + (int)(0xFFFFFFFFu - (unsigned)k[q]);
            } else {
                int w2 = t - NB * NN;                          // b*NA + a
                b = w2 >> 9;
                rr[0] = NN + (w2 & 511);
                const float* row = simT + (size_t)w2 * NN;
#pragma unroll
                for (int q = 0; q < NN / 64; q++) {
                    int n = lane + 64 * q;
                    ins4(pack_key(row[n], (unsigned)n), k);
                }
                merge_top4(k);
#pragma unroll
                for (int q = 0; q < 4; q++) rr[q + 1] = (int)(0xFFFFFFFFu - (unsigned)k[q]);
            }
            if (lane < 25) {
                int i = lane / 5, j = lane - i * 5;
                atomicAdd(W + (size_t)b * NM * NM + (size_t)rr[i] * NM + rr[j], cval);
            }
        }
    }
    grid_barrier(bar);

    // ---- P4: W -> W16 (bf16) + dis = 1/sqrt(rowsum+1+eps) ----
    for (int t = gwave; t < NB * NM; t += GW) {
        const float* row = W + (size_t)t * NM;
        unsigned short* row16 = W16 + (size_t)t * NM;
        float s = 0.f;
#pragma unroll
        for (int q = 0; q < 3; q++) {
            int e = (lane + q * 64) * 4;
            f32x4 v = *(const f32x4*)(row + e);
            s += (v[0] + v[1]) + (v[2] + v[3]);
            u16x4 o;
            o[0] = f2bf(v[0]); o[1] = f2bf(v[1]); o[2] = f2bf(v[2]); o[3] = f2bf(v[3]);
            *(u16x4*)(row16 + e) = o;
        }
        s = wave_allreduce_add(s);
        if (lane == 0) dis[t] = 1.0f / sqrtf(s + 1.0f + 1e-8f);
    }
    grid_barrier(bar);

    // ---- P5: Z0 = dis.*joint (bf16, all m); Xh (B,C,N) = 0.9*feat ----
    for (int t = gwave; t < NB * NC; t += GW) {
        int b = t >> 7, c = t & 127;
        for (int m = lane; m < NM; m += 64) {
            float v = (m < NN) ? feat[(size_t)t * NN + m] : tfT[(size_t)c * NA + (m - NN)];
            Z0[(size_t)t * NM + m] = f2bf(dis[b * NM + m] * v);
            if (m < NN) Xh[(size_t)t * NN + m] = 0.9f * v;
        }
    }
    grid_barrier(bar);

    // ---- P6: prop 1 ----
    for (int bt = blockIdx.x; bt < 384; bt += NBLK) {
        int b = bt / 48, r = bt % 48;
        prop_tile(W16, dis, Z0, Z1, Xh, 0.09f, b, (r >> 1) * 32, (r & 1) * 64, tid);
    }
    grid_barrier(bar);

    // ---- P7: prop 2 ----
    for (int bt = blockIdx.x; bt < 384; bt += NBLK) {
        int b = bt / 48, r = bt % 48;
        prop_tile(W16, dis, Z1, Z0, Xh, 0.009f, b, (r >> 1) * 32, (r & 1) * 64, tid);
    }
    grid_barrier(bar);

    // ---- P8: prop 3 (m<256 only), writes X_hat directly ----
    for (int bt = blockIdx.x; bt < 128; bt += NBLK) {
        int b = bt / 16, r = bt % 16;
        prop_last_tile(W16, dis, Z0, Xh, out_xhat, 0.001f, b, (r >> 1) * 32, (r & 1) * 64, tid);
    }
    grid_barrier(bar);

    // ---- P9: X_E tiled GEMM over X_hat ----
    {
        float (*ta2)[17] = (float(*)[17])smem;
        float (*tz2)[17] = (float(*)[17])(smem + 16 * 17);
        int tx = tid & 15, ty = tid >> 4;
        for (int bt = blockIdx.x; bt < 384; bt += NBLK) {
            __syncthreads();                  // smem reuse fence between iterations
            int b = bt / 48, r = bt % 48;
            int k0 = (r >> 3) * 16, c0 = (r & 7) * 16;
            float acc = 0.f;
            for (int n0 = 0; n0 < NN; n0 += 16) {
                int n = n0 + ty;
                ta2[ty][tx] = adj[(size_t)(b * NN + n) * NK + k0 + tx] * isn[b * NN + n];
                tz2[ty][tx] = out_xhat[((size_t)b * NC + c0 + ty) * NN + n0 + tx];
                __syncthreads();
#pragma unroll
                for (int nn = 0; nn < 16; nn++) acc += ta2[nn][ty] * tz2[tx][nn];
                __syncthreads();
            }
            int k = k0 + ty, c = c0 + tx;
            out_xe[(size_t)(b * NK + k) * NC + c] = inv_edge[b * NK + k] * acc;
        }
    }
}

extern "C" void kernel_launch(void* const* d_in, const int* in_sizes, int n_in,
                              void* d_out, int out_size, void* d_ws, size_t ws_size,
                              hipStream_t stream) {
    (void)in_sizes; (void)n_in; (void)out_size; (void)ws_size;
    const float* features = (const float*)d_in[0];  // (B,C,N)
    const float* adj      = (const float*)d_in[1];  // (B,N,K)
    const float* tf       = (const float*)d_in[2];  // (A,C)
    const float* mem_adj  = (const float*)d_in[3];  // (A,K)
    float* out_xhat = (float*)d_out;                 // (B,C,N)
    float* out_xe   = out_xhat + (size_t)NB * NC * NN;  // (B,K,C)

    int* bar = (int*)d_ws;                           // 512 ints (2 KB), zeroed below
    float* p = (float*)d_ws + 512;
    float* memN_T  = p; p += (size_t)NC * NA;
    float* tfT     = p; p += (size_t)NC * NA;
    float* Xn      = p; p += (size_t)NB * NN * NC;
    float* sim     = p; p += (size_t)NB * NN * NA;
    float* simT    = p; p += (size_t)NB * NN * NA;
    float* sc_adj  = p; p += NB * NK;
    float* inv_edge= p; p += NB * NK;
    float* dmem_inv= p; p += NK;
    float* isn     = p; p += NB * NN;
    float* dis     = p; p += NB * NM;
    float* W       = p; p += (size_t)NB * NM * NM;
    float* Xh      = p; p += (size_t)NB * NC * NN;   // (B,C,N) f32
    unsigned short* W16 = (unsigned short*)p;        // (B,M,M) bf16
    unsigned short* Z0  = W16 + (size_t)NB * NM * NM;
    unsigned short* Z1  = Z0 + (size_t)NB * NC * NM;

    hipMemsetAsync(bar, 0, 512 * sizeof(int), stream);
    k_mega<<<NBLK, 256, 0, stream>>>(features, adj, tf, mem_adj,
                                     memN_T, tfT, Xn, sim, simT,
                                     sc_adj, inv_edge, dmem_inv, isn,
                                     dis, W, Xh, W16, Z0, Z1,
                                     out_xhat, out_xe, bar);
}

// Round 13
// 109.417 us; speedup vs baseline: 4.1281x; 4.1281x over previous
//
#include <hip/hip_runtime.h>

#define NB 8
#define NC 128
#define NN 256
#define NK 96
#define NA 512
#define NM 768   // NN + NA

typedef __attribute__((ext_vector_type(8))) short bf16x8;
typedef __attribute__((ext_vector_type(4))) float f32x4;
typedef __attribute__((ext_vector_type(4))) unsigned short u16x4;

__device__ __forceinline__ float wave_reduce_add(float s) {
    for (int o = 32; o > 0; o >>= 1) s += __shfl_down(s, o, 64);
    return s;
}

// f32 -> bf16 round-to-nearest-even
__device__ __forceinline__ unsigned short f2bf(float x) {
    unsigned u = __float_as_uint(x);
    unsigned r = (u + 0x7FFFu + ((u >> 16) & 1u)) >> 16;
    return (unsigned short)r;
}
__device__ __forceinline__ float bf2f(unsigned short h) {
    return __uint_as_float((unsigned)h << 16);
}

// ---- fused normalize + degrees (128 threads/block) ----
#define NORM_BLKS (NA + NB * NN)
#define DEG_WAVES (NK + NB * NK + NB * NN)
__global__ __launch_bounds__(128) void k_normdeg(const float* __restrict__ tf,
                                                 const float* __restrict__ feat,
                                                 const float* __restrict__ mem_adj,
                                                 const float* __restrict__ adj,
                                                 float* __restrict__ memN_T,
                                                 float* __restrict__ tfT,
                                                 float* __restrict__ Xn,
                                                 float* __restrict__ dmem_inv,
                                                 float* __restrict__ sc_adj,
                                                 float* __restrict__ inv_edge,
                                                 float* __restrict__ isn) {
    __shared__ float p[2];
    int bi = blockIdx.x, c = threadIdx.x;
    if (bi < NA) {
        int a = bi;
        float v = tf[a * NC + c];
        float s = wave_reduce_add(v * v);
        if ((c & 63) == 0) p[c >> 6] = s;
        __syncthreads();
        float norm = sqrtf(p[0] + p[1]);
        memN_T[c * NA + a] = v / fmaxf(norm, 1e-12f);
        tfT[c * NA + a] = v;
    } else if (bi < NORM_BLKS) {
        int g = bi - NA;                 // b*NN + n
        int b = g >> 8, n = g & 255;
        float v = feat[(b * NC + c) * NN + n];
        float s = wave_reduce_add(v * v);
        if ((c & 63) == 0) p[c >> 6] = s;
        __syncthreads();
        float norm = sqrtf(p[0] + p[1]);
        Xn[g * NC + c] = v / fmaxf(norm, 1e-12f);
    } else {
        int wid = (bi - NORM_BLKS) * 2 + (c >> 6);
        int lane = c & 63;
        if (wid < NK) {
            float s = 0.f;
            for (int a = lane; a < NA; a += 64) s += mem_adj[(size_t)a * NK + wid];
            s = wave_reduce_add(s);
            if (lane == 0) dmem_inv[wid] = 1.0f / (s + 1e-8f);
        } else if (wid < NK + NB * NK) {
            int w2 = wid - NK;
            int b = w2 / NK, k = w2 % NK;
            float s = 0.f;
            for (int n = lane; n < NN; n += 64) s += adj[(size_t)(b * NN + n) * NK + k];
            s = wave_reduce_add(s);
            if (lane == 0) {
                sc_adj[w2] = 1.0f / (s + 1e-8f);
                inv_edge[w2] = 1.0f / fmaxf(s, 1e-8f);
            }
        } else if (wid < DEG_WAVES) {
            int w3 = wid - NK - NB * NK;     // b*NN + n
            const float* row = adj + (size_t)w3 * NK;
            float s = (lane < NK) ? row[lane] : 0.f;
            if (lane + 64 < NK) s += row[lane + 64];   // NK=96
            s = wave_reduce_add(s);
            if (lane == 0) isn[w3] = 1.0f / sqrtf(fmaxf(s, 1e-8f));
        }
    }
}

// ---- fused: similarity (+transpose) AND W block builder AND off-diag zero ----
__global__ __launch_bounds__(256) void k_simwb(const float* __restrict__ Xn,
                                               const float* __restrict__ memN_T,
                                               const float* __restrict__ mem_adj,
                                               const float* __restrict__ dmem_inv,
                                               const float* __restrict__ adj,
                                               const float* __restrict__ sc_adj,
                                               float* __restrict__ sim,
                                               float* __restrict__ simT,
                                               float* __restrict__ W) {
    __shared__ float smem[2 * 16 * (NK + 1)];   // 12.4 KB, reused per branch
    int bi = blockIdx.x, tid = threadIdx.x;
    int tx = tid & 15, ty = tid >> 4;
    if (bi < 256) {
        float (*xr)[NC] = (float(*)[NC])smem;
        int g0 = bi * 8;
        int b = g0 >> 8, n0 = g0 & 255;
        for (int i = tid; i < 8 * NC; i += 256) xr[i >> 7][i & 127] = Xn[(size_t)g0 * NC + i];
        __syncthreads();
        float acc0[8] = {0, 0, 0, 0, 0, 0, 0, 0};
        float acc1[8] = {0, 0, 0, 0, 0, 0, 0, 0};
        int a0 = tid, a1 = tid + 256;
        for (int c = 0; c < NC; c++) {
            float m0 = memN_T[c * NA + a0];
            float m1 = memN_T[c * NA + a1];
#pragma unroll
            for (int r = 0; r < 8; r++) { acc0[r] += xr[r][c] * m0; acc1[r] += xr[r][c] * m1; }
        }
#pragma unroll
        for (int r = 0; r < 8; r++) {
            sim[(size_t)(g0 + r) * NA + a0] = acc0[r];
            sim[(size_t)(g0 + r) * NA + a1] = acc1[r];
        }
        float* tp0 = simT + ((size_t)(b * NA + a0)) * NN + n0;
        float* tp1 = simT + ((size_t)(b * NA + a1)) * NN + n0;
        f32x4 u, v;
        u[0] = acc0[0]; u[1] = acc0[1]; u[2] = acc0[2]; u[3] = acc0[3];
        v[0] = acc0[4]; v[1] = acc0[5]; v[2] = acc0[6]; v[3] = acc0[7];
        *(f32x4*)tp0 = u; *(f32x4*)(tp0 + 4) = v;
        u[0] = acc1[0]; u[1] = acc1[1]; u[2] = acc1[2]; u[3] = acc1[3];
        v[0] = acc1[4]; v[1] = acc1[5]; v[2] = acc1[6]; v[3] = acc1[7];
        *(f32x4*)tp1 = u; *(f32x4*)(tp1 + 4) = v;
    } else if (bi < 1280) {
        float (*ta)[NK + 1] = (float(*)[NK + 1])smem;
        float (*tb)[NK + 1] = (float(*)[NK + 1])(smem + 16 * (NK + 1));
        int t = bi - 256;
        int a0 = (t >> 5) * 16, a1 = (t & 31) * 16;
        for (int i = tid; i < 16 * NK; i += 256) {
            int r = i / NK, j = i % NK;
            ta[r][j] = mem_adj[(a0 + r) * NK + j] * dmem_inv[j];
            tb[r][j] = mem_adj[(a1 + r) * NK + j];
        }
        __syncthreads();
        float s = 0.f;
        for (int j = 0; j < NK; j++) s += ta[ty][j] * tb[tx][j];
        int row = NN + a0 + ty, col = NN + a1 + tx;
        for (int b = 0; b < NB; b++) W[(size_t)b * NM * NM + (size_t)row * NM + col] = s;
    } else if (bi < 3328) {
        float (*ta)[NK + 1] = (float(*)[NK + 1])smem;
        float (*tb)[NK + 1] = (float(*)[NK + 1])(smem + 16 * (NK + 1));
        int t = bi - 1280;
        int n1 = (t & 15) * 16, n0 = ((t >> 4) & 15) * 16, b = t >> 8;
        const float* adjb = adj + (size_t)b * NN * NK;
        const float* scb = sc_adj + b * NK;
        for (int i = tid; i < 16 * NK; i += 256) {
            int r = i / NK, j = i % NK;
            ta[r][j] = adjb[(n0 + r) * NK + j] * scb[j];
            tb[r][j] = adjb[(n1 + r) * NK + j];
        }
        __syncthreads();
        float s = 0.f;
        for (int j = 0; j < NK; j++) s += ta[ty][j] * tb[tx][j];
        W[(size_t)b * NM * NM + (size_t)(n0 + ty) * NM + (n1 + tx)] = s;
    } else {
        int t = bi - 3328;               // [0, 512)
        int b = t >> 6;
        f32x4 z; z[0] = 0.f; z[1] = 0.f; z[2] = 0.f; z[3] = 0.f;
#pragma unroll
        for (int q = 0; q < 4; q++) {
            int v = (t & 63) * 1024 + q * 256 + tid;   // [0, 65536) f32x4 slots/batch
            int row, col4;
            if (v < 32768) { row = v >> 7; col4 = 64 + (v & 127); }
            else { int v2 = v - 32768; row = 256 + (v2 >> 6); col4 = v2 & 63; }
            *(f32x4*)(W + (size_t)b * NM * NM + (size_t)row * NM + col4 * 4) = z;
        }
    }
}

// ---- sortable key: higher value wins, tie -> lower index (== lax.top_k order) ----
__device__ __forceinline__ unsigned long long pack_key(float v, unsigned idx) {
    unsigned u = __float_as_uint(v);
    u = (u & 0x80000000u) ? ~u : (u | 0x80000000u);
    return ((unsigned long long)u << 32) | (unsigned long long)(0xFFFFFFFFu - idx);
}

__device__ __forceinline__ void ins4(unsigned long long v, unsigned long long* k) {
    if (v > k[3]) {
        if (v > k[1]) {
            if (v > k[0]) { k[3] = k[2]; k[2] = k[1]; k[1] = k[0]; k[0] = v; }
            else         { k[3] = k[2]; k[2] = k[1]; k[1] = v; }
        } else {
            if (v > k[2]) { k[3] = k[2]; k[2] = v; }
            else          { k[3] = v; }
        }
    }
}

__device__ __forceinline__ void merge_top4(unsigned long long* k) {
#pragma unroll
    for (int d = 1; d < 64; d <<= 1) {
        unsigned long long p0 = __shfl_xor(k[0], d, 64);
        unsigned long long p1 = __shfl_xor(k[1], d, 64);
        unsigned long long p2 = __shfl_xor(k[2], d, 64);
        unsigned long long p3 = __shfl_xor(k[3], d, 64);
        unsigned long long c0 = k[0] > p3 ? k[0] : p3;
        unsigned long long c1 = k[1] > p2 ? k[1] : p2;
        unsigned long long c2 = k[2] > p1 ? k[2] : p1;
        unsigned long long c3 = k[3] > p0 ? k[3] : p0;
        unsigned long long d0 = c0 > c2 ? c0 : c2, d2 = c0 > c2 ? c2 : c0;
        unsigned long long d1 = c1 > c3 ? c1 : c3, d3 = c1 > c3 ? c3 : c1;
        k[0] = d0 > d1 ? d0 : d1; k[1] = d0 > d1 ? d1 : d0;
        k[2] = d2 > d3 ? d2 : d3; k[3] = d2 > d3 ? d3 : d2;
    }
}

// ---- fused top-4 + cross-column clique scatter (after k_simwb) ----
__global__ __launch_bounds__(256) void k_knnrev(const float* __restrict__ sim,
                                                const float* __restrict__ simT,
                                                float* __restrict__ W) {
    int wid = (blockIdx.x * 256 + threadIdx.x) >> 6;
    int lane = threadIdx.x & 63;
    unsigned long long k[4] = {0, 0, 0, 0};
    const float cval = 1.0f / (5.0f + 1e-8f);
    int b, rr[5];
    if (wid < NB * NN) {
        b = wid >> 8;
        rr[0] = wid & 255;
        const float* row = sim + (size_t)wid * NA;
#pragma unroll
        for (int t = 0; t < NA / 64; t++) {
            int a = lane + 64 * t;
            ins4(pack_key(row[a], (unsigned)a), k);
        }
        merge_top4(k);
#pragma unroll
        for (int t = 0; t < 4; t++) rr[t + 1] = NN + (int)(0xFFFFFFFFu - (unsigned)k[t]);
    } else {
        int w2 = wid - NB * NN;              // b*NA + a
        b = w2 >> 9;
        rr[0] = NN + (w2 & 511);
        const float* row = simT + (size_t)w2 * NN;
#pragma unroll
        for (int t = 0; t < NN / 64; t++) {
            int n = lane + 64 * t;
            ins4(pack_key(row[n], (unsigned)n), k);
        }
        merge_top4(k);
#pragma unroll
        for (int t = 0; t < 4; t++) rr[t + 1] = (int)(0xFFFFFFFFu - (unsigned)k[t]);
    }
    if (lane < 25) {
        int i = lane / 5, j = lane - i * 5;
        atomicAdd(W + (size_t)b * NM * NM + (size_t)rr[i] * NM + rr[j], cval);
    }
}

// ---- fused: W(f32) -> W16(bf16) + dis = 1/sqrt(rowsum+1+eps); one wave per row ----
__global__ __launch_bounds__(256) void k_w16dis(const float* __restrict__ W,
                                                unsigned short* __restrict__ W16,
                                                float* __restrict__ dis) {
    int wid = (blockIdx.x * 256 + threadIdx.x) >> 6;  // b*NM + row
    int lane = threadIdx.x & 63;
    if (wid >= NB * NM) return;
    const float* row = W + (size_t)wid * NM;
    unsigned short* row16 = W16 + (size_t)wid * NM;
    float s = 0.f;
#pragma unroll
    for (int t = 0; t < 3; t++) {
        int e = (lane + t * 64) * 4;
        f32x4 v = *(const f32x4*)(row + e);
        s += (v[0] + v[1]) + (v[2] + v[3]);
        u16x4 o;
        o[0] = f2bf(v[0]); o[1] = f2bf(v[1]); o[2] = f2bf(v[2]); o[3] = f2bf(v[3]);
        *(u16x4*)(row16 + e) = o;
    }
    s = wave_reduce_add(s);
    if (lane == 0) dis[wid] = 1.0f / sqrtf(s + 1.0f + 1e-8f);
}

// ---- Z0[b,c,m] = dis[b,m]*joint (bf16, all m) ----
__global__ void k_y0(const float* __restrict__ feat, const float* __restrict__ tfT,
                     const float* __restrict__ dis, unsigned short* __restrict__ Z0) {
    int bc = blockIdx.x;            // b*NC + c
    int b = bc >> 7, c = bc & 127;
    for (int m = threadIdx.x; m < NM; m += 256) {
        float v = (m < NN) ? feat[(size_t)bc * NN + m] : tfT[(size_t)c * NA + (m - NN)];
        Z0[(size_t)bc * NM + m] = f2bf(dis[b * NM + m] * v);
    }
}

// ---- MFMA propagation on Z = D^-1/2 Y (full step):
//      s = W @ Zin ; o = dis*(s + Zin) ; Zout = dis*o
//      Xh (m<N rows only): INIT ? Xh = 0.9*feat + coef*o : Xh += coef*o
template<bool INIT>
__global__ __launch_bounds__(256) void k_prop(const unsigned short* __restrict__ W16,
                                              const float* __restrict__ dis,
                                              const unsigned short* __restrict__ Zin,
                                              unsigned short* __restrict__ Zout,
                                              float* __restrict__ Xh,
                                              const float* __restrict__ feat, float coef) {
    int b = blockIdx.z;
    int m0 = blockIdx.x * 32;   // 24 tiles
    int c0 = blockIdx.y * 64;   // 2 tiles
    int tid = threadIdx.x;
    int w = tid >> 6, l = tid & 63;
    int wm = w >> 1, wc = w & 1;
    int lr = l & 15, lg = l >> 4;

    const unsigned short* Ap = W16 + ((size_t)b * NM + m0 + wm * 16 + lr) * NM + lg * 8;
    const unsigned short* Bp = Zin + ((size_t)b * NC + c0 + wc * 32 + lr) * NM + lg * 8;

    f32x4 acc[2];
#pragma unroll
    for (int f = 0; f < 2; f++) { acc[f][0] = 0.f; acc[f][1] = 0.f; acc[f][2] = 0.f; acc[f][3] = 0.f; }

    bf16x8 a0 = *(const bf16x8*)(Ap);
    bf16x8 b0[2];
#pragma unroll
    for (int f = 0; f < 2; f++) b0[f] = *(const bf16x8*)(Bp + (size_t)(f * 16) * NM);

    for (int k0 = 0; k0 < NM - 32; k0 += 32) {
        bf16x8 a1 = *(const bf16x8*)(Ap + k0 + 32);
        bf16x8 b1[2];
#pragma unroll
        for (int f = 0; f < 2; f++) b1[f] = *(const bf16x8*)(Bp + (size_t)(f * 16) * NM + k0 + 32);
#pragma unroll
        for (int f = 0; f < 2; f++)
            acc[f] = __builtin_amdgcn_mfma_f32_16x16x32_bf16(a0, b0[f], acc[f], 0, 0, 0);
        a0 = a1;
#pragma unroll
        for (int f = 0; f < 2; f++) b0[f] = b1[f];
    }
#pragma unroll
    for (int f = 0; f < 2; f++)
        acc[f] = __builtin_amdgcn_mfma_f32_16x16x32_bf16(a0, b0[f], acc[f], 0, 0, 0);

    int mb = m0 + wm * 16 + lg * 4;
    f32x4 dv = *(const f32x4*)(dis + b * NM + mb);
    bool doXh = (m0 < NN);          // m-tile 32-aligned: whole tile is < N or >= N
#pragma unroll
    for (int f = 0; f < 2; f++) {
        int c = c0 + wc * 32 + f * 16 + lr;
        size_t off = ((size_t)b * NC + c) * NM + mb;
        u16x4 zi = *(const u16x4*)(Zin + off);
        u16x4 zo;
        f32x4 xh;
        size_t offh = ((size_t)b * NC + c) * NN + mb;
        if (doXh) {
            if (INIT) {
                f32x4 fv = *(const f32x4*)(feat + offh);
                xh[0] = 0.9f * fv[0]; xh[1] = 0.9f * fv[1];
                xh[2] = 0.9f * fv[2]; xh[3] = 0.9f * fv[3];
            } else {
                xh = *(const f32x4*)(Xh + offh);
            }
        }
#pragma unroll
        for (int r = 0; r < 4; r++) {
            float o = dv[r] * (acc[f][r] + bf2f(zi[r]));
            if (doXh) xh[r] += coef * o;
            zo[r] = f2bf(dv[r] * o);
        }
        if (doXh) *(f32x4*)(Xh + offh) = xh;
        *(u16x4*)(Zout + off) = zo;
    }
}

// ---- last propagation: only m<256 matters; writes X_hat (B,C,N) directly ----
__global__ __launch_bounds__(256) void k_prop_last(const unsigned short* __restrict__ W16,
                                                   const float* __restrict__ dis,
                                                   const unsigned short* __restrict__ Zin,
                                                   const float* __restrict__ Xh,
                                                   float* __restrict__ out_xhat, float coef) {
    int b = blockIdx.z;
    int m0 = blockIdx.x * 32;   // 8 tiles -> m < 256
    int c0 = blockIdx.y * 64;
    int tid = threadIdx.x;
    int w = tid >> 6, l = tid & 63;
    int wm = w >> 1, wc = w & 1;
    int lr = l & 15, lg = l >> 4;

    const unsigned short* Ap = W16 + ((size_t)b * NM + m0 + wm * 16 + lr) * NM + lg * 8;
    const unsigned short* Bp = Zin + ((size_t)b * NC + c0 + wc * 32 + lr) * NM + lg * 8;

    f32x4 acc[2];
#pragma unroll
    for (int f = 0; f < 2; f++) { acc[f][0] = 0.f; acc[f][1] = 0.f; acc[f][2] = 0.f; acc[f][3] = 0.f; }

    bf16x8 a0 = *(const bf16x8*)(Ap);
    bf16x8 b0[2];
#pragma unroll
    for (int f = 0; f < 2; f++) b0[f] = *(const bf16x8*)(Bp + (size_t)(f * 16) * NM);

    for (int k0 = 0; k0 < NM - 32; k0 += 32) {
        bf16x8 a1 = *(const bf16x8*)(Ap + k0 + 32);
        bf16x8 b1[2];
#pragma unroll
        for (int f = 0; f < 2; f++) b1[f] = *(const bf16x8*)(Bp + (size_t)(f * 16) * NM + k0 + 32);
#pragma unroll
        for (int f = 0; f < 2; f++)
            acc[f] = __builtin_amdgcn_mfma_f32_16x16x32_bf16(a0, b0[f], acc[f], 0, 0, 0);
        a0 = a1;
#pragma unroll
        for (int f = 0; f < 2; f++) b0[f] = b1[f];
    }
#pragma unroll
    for (int f = 0; f < 2; f++)
        acc[f] = __builtin_amdgcn_mfma_f32_16x16x32_bf16(a0, b0[f], acc[f], 0, 0, 0);

    int mb = m0 + wm * 16 + lg * 4;   // < 256
    f32x4 dv = *(const f32x4*)(dis + b * NM + mb);
#pragma unroll
    for (int f = 0; f < 2; f++) {
        int c = c0 + wc * 32 + f * 16 + lr;
        size_t offM = ((size_t)b * NC + c) * NM + mb;
        u16x4 zi = *(const u16x4*)(Zin + offM);
        f32x4 xh = *(const f32x4*)(Xh + ((size_t)b * NC + c) * NN + mb);
        f32x4 ov;
#pragma unroll
        for (int r = 0; r < 4; r++) {
            float o = dv[r] * (acc[f][r] + bf2f(zi[r]));
            ov[r] = xh[r] + coef * o;
        }
        *(f32x4*)(out_xhat + ((size_t)b * NC + c) * NN + mb) = ov;
    }
}

// ---- X_E[b,k,c] = inv_edge[b,k] * sum_n (adj[b,n,k]*isn[b,n]) * Xhat[b,c,n] ----
__global__ __launch_bounds__(256) void k_xe(const float* __restrict__ Xhat,
                                            const float* __restrict__ adj,
                                            const float* __restrict__ isn,
                                            const float* __restrict__ inv_edge,
                                            float* __restrict__ outE) {
    __shared__ float ta[16][17];  // [n_local][k_local]
    __shared__ float tz[16][17];  // [c_local][n_local]
    int b = blockIdx.z;
    int k0 = blockIdx.y * 16;     // 6 tiles
    int c0 = blockIdx.x * 16;     // 8 tiles
    int tx = threadIdx.x & 15;
    int ty = threadIdx.x >> 4;
    float acc = 0.f;
    for (int n0 = 0; n0 < NN; n0 += 16) {
        int n = n0 + ty;
        ta[ty][tx] = adj[(size_t)(b * NN + n) * NK + k0 + tx] * isn[b * NN + n];
        tz[ty][tx] = Xhat[((size_t)b * NC + c0 + ty) * NN + n0 + tx];
        __syncthreads();
#pragma unroll
        for (int nn = 0; nn < 16; nn++) acc += ta[nn][ty] * tz[tx][nn];
        __syncthreads();
    }
    int k = k0 + ty, c = c0 + tx;
    outE[(size_t)(b * NK + k) * NC + c] = inv_edge[b * NK + k] * acc;
}

extern "C" void kernel_launch(void* const* d_in, const int* in_sizes, int n_in,
                              void* d_out, int out_size, void* d_ws, size_t ws_size,
                              hipStream_t stream) {
    (void)in_sizes; (void)n_in; (void)out_size; (void)ws_size;
    const float* features = (const float*)d_in[0];  // (B,C,N)
    const float* adj      = (const float*)d_in[1];  // (B,N,K)
    const float* tf       = (const float*)d_in[2];  // (A,C)
    const float* mem_adj  = (const float*)d_in[3];  // (A,K)
    float* out_xhat = (float*)d_out;                 // (B,C,N)
    float* out_xe   = out_xhat + (size_t)NB * NC * NN;  // (B,K,C)

    float* p = (float*)d_ws;
    float* memN_T  = p; p += (size_t)NC * NA;
    float* tfT     = p; p += (size_t)NC * NA;
    float* Xn      = p; p += (size_t)NB * NN * NC;
    float* sim     = p; p += (size_t)NB * NN * NA;
    float* simT    = p; p += (size_t)NB * NN * NA;
    float* sc_adj  = p; p += NB * NK;
    float* inv_edge= p; p += NB * NK;
    float* dmem_inv= p; p += NK;
    float* isn     = p; p += NB * NN;
    float* dis     = p; p += NB * NM;
    float* W       = p; p += (size_t)NB * NM * NM;
    float* Xh      = p; p += (size_t)NB * NC * NN;   // (B,C,N) f32 (m<N only)
    unsigned short* W16 = (unsigned short*)p;        // (B,M,M) bf16
    unsigned short* Z0  = W16 + (size_t)NB * NM * NM;
    unsigned short* Z1  = Z0 + (size_t)NB * NC * NM;

    k_normdeg<<<NORM_BLKS + (DEG_WAVES + 1) / 2, 128, 0, stream>>>(
        tf, features, mem_adj, adj, memN_T, tfT, Xn, dmem_inv, sc_adj, inv_edge, isn);
    k_simwb<<<3840, 256, 0, stream>>>(Xn, memN_T, mem_adj, dmem_inv, adj, sc_adj,
                                      sim, simT, W);
    k_knnrev<<<(NB * NN + NB * NA) / 4, 256, 0, stream>>>(sim, simT, W);
    k_w16dis<<<NB * NM / 4, 256, 0, stream>>>(W, W16, dis);
    k_y0<<<NB * NC, 256, 0, stream>>>(features, tfT, dis, Z0);
    dim3 pg(NM / 32, NC / 64, NB);
    k_prop<true><<<pg, 256, 0, stream>>>(W16, dis, Z0, Z1, Xh, features, 0.09f);
    k_prop<false><<<pg, 256, 0, stream>>>(W16, dis, Z1, Z0, Xh, features, 0.009f);
    dim3 pl(NN / 32, NC / 64, NB);
    k_prop_last<<<pl, 256, 0, stream>>>(W16, dis, Z0, Xh, out_xhat, 0.001f);
    k_xe<<<dim3(NC / 16, NK / 16, NB), 256, 0, stream>>>(out_xhat, adj, isn, inv_edge, out_xe);
}